// Round 5
// baseline (486.334 us; speedup 1.0000x reference)
//
#include <hip/hip_runtime.h>

#define BETA 0.9f
#define THRESH 1.0f

constexpr int Bsz  = 64;
constexpr int Din  = 1024;
constexpr int Dout = 1024;
constexpr int KCH  = 4;              // split-K chunks
constexpr int KLEN = Din / KCH;      // 256
constexpr int NBJ  = Bsz * Dout;     // 65536

typedef float f4 __attribute__((ext_vector_type(4)));

// ---------------------------------------------------------------------------
// A1: split-K partial GEMM with ROW-COALESCED W reads.
// Block (b, kc): 256 threads, thread t owns f4 columns j = 4t..4t+3 (full
// 1024-j row). Inner loop over the 256-k chunk: W row k is read as 256
// contiguous float4 = 4 KB per block-load (1 KB/wave — full coalescing,
// vs R2-R4's 256 B stride-4KB column reads that missed L1 every time);
// x[b,k] is block-uniform (scalar path). grid = 64*4 = 256 blocks.
// W traffic: 1 MB/block from L2 (W is 4 MB, L2-resident per XCD).
// partial[kc][b][j] = 1 MB workspace (same footprint R0 proved safe).
// ---------------------------------------------------------------------------
__global__ __launch_bounds__(256) void gemm_partial(const float* __restrict__ x,
                                                    const float* __restrict__ W,
                                                    float* __restrict__ partial) {
    const int blk = blockIdx.x;          // 0..255
    const int b   = blk >> 2;            // sample
    const int kc  = blk & 3;             // k-chunk
    const int t   = threadIdx.x;

    const float* xr = x + b * Din + kc * KLEN;
    const f4*    Wr = (const f4*)(W + (size_t)(kc * KLEN) * Dout) + t;

    f4 acc = {0.f, 0.f, 0.f, 0.f};
#pragma unroll 8
    for (int k = 0; k < KLEN; ++k) {
        const float xs = xr[k];          // uniform
        const f4    w  = Wr[(size_t)k * (Dout / 4)];
        acc.x = fmaf(xs, w.x, acc.x);
        acc.y = fmaf(xs, w.y, acc.y);
        acc.z = fmaf(xs, w.z, acc.z);
        acc.w = fmaf(xs, w.w, acc.w);
    }
    ((f4*)partial)[(size_t)(kc * Bsz + b) * (Dout / 4) + t] = acc;
}

// ---------------------------------------------------------------------------
// A2: reduce the 4 partials + LIF elementwise + E_b update + stash one_m.
// grid = 256 blocks x 256 threads, one element per thread. ~3 MB traffic.
// ---------------------------------------------------------------------------
__global__ __launch_bounds__(256) void lif_elem(const float* __restrict__ partial,
                                                const float* __restrict__ bias,
                                                const float* __restrict__ u0,
                                                const float* __restrict__ E_b,
                                                float* __restrict__ out_spk,
                                                float* __restrict__ out_u,
                                                float* __restrict__ out_Eb,
                                                float* __restrict__ one_m_ws) {
    const int idx = blockIdx.x * 256 + threadIdx.x;   // 0..65535
    const int j   = idx & (Dout - 1);

    float I = partial[idx] + partial[NBJ + idx] + partial[2 * NBJ + idx]
            + partial[3 * NBJ + idx] + bias[j];
    float v   = fmaf(BETA, u0[idx], I);
    float vt  = v - THRESH;
    float spk = vt > 0.f ? 1.f : 0.f;
    float a   = 1.f + fabsf(vt);
    float om  = 1.f - THRESH / (a * a);   // one_m = 1 - THRESH*sg

    out_spk[idx]  = spk;
    out_u[idx]    = v - THRESH * spk;     // soft reset
    out_Eb[idx]   = om * fmaf(BETA, E_b[idx], 1.f);
    one_m_ws[idx] = om;
}

// ---------------------------------------------------------------------------
// B: the 512 MB E_W stream. BYTE-IDENTICAL to R4 (grid-stride, 4 independent
// full-grid-stride f4 streams/iter, plain stores) — untouched for clean A/B.
// ---------------------------------------------------------------------------
constexpr unsigned NV4   = (unsigned)Bsz * Din * Dout / 4;  // 16777216 vec4
constexpr unsigned EW_TH = 2048u * 256u;                    // 524288 threads
constexpr unsigned EW_IT = NV4 / (EW_TH * 4u);              // 8 outer iters

__global__ __launch_bounds__(256) void ew_update(const float* __restrict__ E_W,
                                                 const float* __restrict__ x,
                                                 const float* __restrict__ one_m,
                                                 float* __restrict__ out_EW) {
    const unsigned tid = blockIdx.x * 256u + threadIdx.x;
    const f4* __restrict__ src = (const f4*)E_W;
    f4* __restrict__       dst = (f4*)out_EW;
    const f4* __restrict__ om4 = (const f4*)one_m;

    unsigned base = tid;                 // 4 streams: base + {0,1,2,3}*EW_TH
#pragma unroll
    for (unsigned it = 0; it < EW_IT; ++it, base += 4u * EW_TH) {
        const unsigned v0 = base, v1 = base + EW_TH, v2 = base + 2u * EW_TH,
                       v3 = base + 3u * EW_TH;
        const f4 e0 = src[v0];
        const f4 e1 = src[v1];
        const f4 e2 = src[v2];
        const f4 e3 = src[v3];

        const unsigned b0 = v0 >> 18, b1 = v1 >> 18, b2 = v2 >> 18, b3 = v3 >> 18;
        const f4 m0 = om4[(b0 << 8) | (v0 & 255u)];
        const f4 m1 = om4[(b1 << 8) | (v1 & 255u)];
        const f4 m2 = om4[(b2 << 8) | (v2 & 255u)];
        const f4 m3 = om4[(b3 << 8) | (v3 & 255u)];
        const float x0 = x[(b0 << 10) | ((v0 >> 8) & 1023u)];
        const float x1 = x[(b1 << 10) | ((v1 >> 8) & 1023u)];
        const float x2 = x[(b2 << 10) | ((v2 >> 8) & 1023u)];
        const float x3 = x[(b3 << 10) | ((v3 >> 8) & 1023u)];

        f4 r0, r1, r2, r3;
        r0.x = m0.x * fmaf(BETA, e0.x, x0); r0.y = m0.y * fmaf(BETA, e0.y, x0);
        r0.z = m0.z * fmaf(BETA, e0.z, x0); r0.w = m0.w * fmaf(BETA, e0.w, x0);
        r1.x = m1.x * fmaf(BETA, e1.x, x1); r1.y = m1.y * fmaf(BETA, e1.y, x1);
        r1.z = m1.z * fmaf(BETA, e1.z, x1); r1.w = m1.w * fmaf(BETA, e1.w, x1);
        r2.x = m2.x * fmaf(BETA, e2.x, x2); r2.y = m2.y * fmaf(BETA, e2.y, x2);
        r2.z = m2.z * fmaf(BETA, e2.z, x2); r2.w = m2.w * fmaf(BETA, e2.w, x2);
        r3.x = m3.x * fmaf(BETA, e3.x, x3); r3.y = m3.y * fmaf(BETA, e3.y, x3);
        r3.z = m3.z * fmaf(BETA, e3.z, x3); r3.w = m3.w * fmaf(BETA, e3.w, x3);

        dst[v0] = r0;
        dst[v1] = r1;
        dst[v2] = r2;
        dst[v3] = r3;
    }
}

extern "C" void kernel_launch(void* const* d_in, const int* in_sizes, int n_in,
                              void* d_out, int out_size, void* d_ws, size_t ws_size,
                              hipStream_t stream) {
    const float* x    = (const float*)d_in[0];
    const float* W    = (const float*)d_in[1];
    const float* bias = (const float*)d_in[2];
    const float* u0   = (const float*)d_in[3];
    const float* E_W  = (const float*)d_in[4];
    const float* E_b  = (const float*)d_in[5];

    float* out     = (float*)d_out;
    float* out_spk = out;                       // [64,1024]
    float* out_u   = out + NBJ;                 // [64,1024]
    float* out_EW  = out + 2 * NBJ;             // [64,1024,1024]
    float* out_Eb  = out + 2 * NBJ + (size_t)Bsz * Din * Dout;  // [64,1024]

    float* partial = (float*)d_ws;              // 4 * 65536 floats = 1 MB
    float* one_m   = partial + KCH * NBJ;       // 256 KB (1.25 MB total, = R0)

    gemm_partial<<<Bsz * KCH, 256, 0, stream>>>(x, W, partial);
    lif_elem<<<NBJ / 256, 256, 0, stream>>>(partial, bias, u0, E_b,
                                            out_spk, out_u, out_Eb, one_m);
    ew_update<<<2048, 256, 0, stream>>>(E_W, x, one_m, out_EW);
}

// Round 6
// 462.055 us; speedup vs baseline: 1.0525x; 1.0525x over previous
//
#include <hip/hip_runtime.h>

#define BETA 0.9f
#define THRESH 1.0f

constexpr int Bsz  = 64;
constexpr int Din  = 1024;
constexpr int Dout = 1024;
constexpr int NBJ  = Bsz * Dout;        // 65536

typedef float f4 __attribute__((ext_vector_type(4)));

// ---------------------------------------------------------------------------
// A: fused GEMM + LIF elementwise (byte-identical to R4's proven kernel,
// ~11-15 us under the 2-fill window model; W column reads are L2-served).
// grid = Bsz * (Dout/64) = 1024 blocks x 256 threads.
// ---------------------------------------------------------------------------
__global__ __launch_bounds__(256) void gemm_lif(const float* __restrict__ x,
                                                const float* __restrict__ W,
                                                const float* __restrict__ bias,
                                                const float* __restrict__ u0,
                                                const float* __restrict__ E_b,
                                                float* __restrict__ out_spk,
                                                float* __restrict__ out_u,
                                                float* __restrict__ out_Eb,
                                                float* __restrict__ one_m_ws) {
    __shared__ float red[4][64];
    const int blk = blockIdx.x;
    const int b   = blk >> 4;           // sample 0..63
    const int jg  = blk & 15;           // 64-column group
    const int t   = threadIdx.x;
    const int jl  = t & 63;
    const int ks  = t >> 6;             // k-slice == wave id
    const int j   = (jg << 6) + jl;

    const float* xr = x + b * Din + (ks << 8);
    const float* Wc = W + (size_t)(ks << 8) * Dout + j;

    float acc = 0.f;
#pragma unroll 16
    for (int k = 0; k < 256; ++k)
        acc = fmaf(xr[k], Wc[(size_t)k * Dout], acc);

    red[ks][jl] = acc;
    __syncthreads();

    if (t < 64) {
        const int idx = b * Dout + j;
        float I   = red[0][t] + red[1][t] + red[2][t] + red[3][t] + bias[j];
        float v   = fmaf(BETA, u0[idx], I);
        float vt  = v - THRESH;
        float spk = vt > 0.f ? 1.f : 0.f;
        float a   = 1.f + fabsf(vt);
        float om  = 1.f - THRESH / (a * a);

        out_spk[idx]  = spk;
        out_u[idx]    = v - THRESH * spk;
        out_Eb[idx]   = om * fmaf(BETA, E_b[idx], 1.f);
        one_m_ws[idx] = om;
    }
}

// ---------------------------------------------------------------------------
// B: the 512 MB E_W stream — R0's proven no-loop massive-parallelism shape
// (fastest measured: ~105 us vs 140-185 for every loop-carrying variant; the
// compiler serializes in-loop load/store round-trips at VGPR~32, while the
// no-loop kernel gets MLP from occupancy). Tweak vs R0: TWO adjacent float4
// per thread (32 B/lane contiguous, two independent loads in flight/thread),
// 32768 blocks x 256 threads, plain stores (nt store proven 2x slower R2/R3).
// E_W_new[b,i,j] = one_m[b,j] * (BETA*E_W[b,i,j] + x[b,i])
// ---------------------------------------------------------------------------
__global__ __launch_bounds__(256) void ew_update(const float* __restrict__ E_W,
                                                 const float* __restrict__ x,
                                                 const float* __restrict__ one_m,
                                                 float* __restrict__ out_EW) {
    const unsigned gid = blockIdx.x * 256u + threadIdx.x;   // < 8388608
    const unsigned v0  = gid << 1, v1 = v0 | 1u;            // adjacent vec4s

    const f4* __restrict__ src = (const f4*)E_W;
    f4* __restrict__       dst = (f4*)out_EW;
    const f4* __restrict__ om4 = (const f4*)one_m;

    // both HBM loads issued before any dependent use
    const f4 e0 = src[v0];
    const f4 e1 = src[v1];

    const unsigned b   = v0 >> 18;          // sample (shared: v1 adjacent)
    const unsigned rem = v0 & 262143u;
    const unsigned i   = rem >> 8;          // row (shared)
    const unsigned jv0 = rem & 255u;        // even; jv1 = jv0+1

    const f4    m0 = om4[(b << 8) | jv0];
    const f4    m1 = om4[(b << 8) | (jv0 + 1u)];
    const float xs = x[(b << 10) | i];      // block-uniform scalar

    f4 r0, r1;
    r0.x = m0.x * fmaf(BETA, e0.x, xs); r0.y = m0.y * fmaf(BETA, e0.y, xs);
    r0.z = m0.z * fmaf(BETA, e0.z, xs); r0.w = m0.w * fmaf(BETA, e0.w, xs);
    r1.x = m1.x * fmaf(BETA, e1.x, xs); r1.y = m1.y * fmaf(BETA, e1.y, xs);
    r1.z = m1.z * fmaf(BETA, e1.z, xs); r1.w = m1.w * fmaf(BETA, e1.w, xs);

    dst[v0] = r0;
    dst[v1] = r1;
}

extern "C" void kernel_launch(void* const* d_in, const int* in_sizes, int n_in,
                              void* d_out, int out_size, void* d_ws, size_t ws_size,
                              hipStream_t stream) {
    const float* x    = (const float*)d_in[0];
    const float* W    = (const float*)d_in[1];
    const float* bias = (const float*)d_in[2];
    const float* u0   = (const float*)d_in[3];
    const float* E_W  = (const float*)d_in[4];
    const float* E_b  = (const float*)d_in[5];

    float* out     = (float*)d_out;
    float* out_spk = out;                       // [64,1024]
    float* out_u   = out + NBJ;                 // [64,1024]
    float* out_EW  = out + 2 * NBJ;             // [64,1024,1024]
    float* out_Eb  = out + 2 * NBJ + (size_t)Bsz * Din * Dout;  // [64,1024]

    float* one_m = (float*)d_ws;                // 256 KB

    gemm_lif<<<Bsz * (Dout / 64), 256, 0, stream>>>(x, W, bias, u0, E_b,
                                                    out_spk, out_u, out_Eb, one_m);
    ew_update<<<(Bsz * Din * Dout / 8) / 256, 256, 0, stream>>>(E_W, x, one_m, out_EW);
}

// Round 7
// 458.966 us; speedup vs baseline: 1.0596x; 1.0067x over previous
//
#include <hip/hip_runtime.h>

#define BETA 0.9f
#define THRESH 1.0f

constexpr int Bsz  = 64;
constexpr int Din  = 1024;
constexpr int Dout = 1024;
constexpr int NBJ  = Bsz * Dout;        // 65536

typedef float f4 __attribute__((ext_vector_type(4)));

// ---------------------------------------------------------------------------
// A: fused GEMM + LIF elementwise (byte-identical to R4/R6 — ~12 us).
// grid = Bsz * (Dout/64) = 1024 blocks x 256 threads.
// ---------------------------------------------------------------------------
__global__ __launch_bounds__(256) void gemm_lif(const float* __restrict__ x,
                                                const float* __restrict__ W,
                                                const float* __restrict__ bias,
                                                const float* __restrict__ u0,
                                                const float* __restrict__ E_b,
                                                float* __restrict__ out_spk,
                                                float* __restrict__ out_u,
                                                float* __restrict__ out_Eb,
                                                float* __restrict__ one_m_ws) {
    __shared__ float red[4][64];
    const int blk = blockIdx.x;
    const int b   = blk >> 4;           // sample 0..63
    const int jg  = blk & 15;           // 64-column group
    const int t   = threadIdx.x;
    const int jl  = t & 63;
    const int ks  = t >> 6;             // k-slice == wave id
    const int j   = (jg << 6) + jl;

    const float* xr = x + b * Din + (ks << 8);
    const float* Wc = W + (size_t)(ks << 8) * Dout + j;

    float acc = 0.f;
#pragma unroll 16
    for (int k = 0; k < 256; ++k)
        acc = fmaf(xr[k], Wc[(size_t)k * Dout], acc);

    red[ks][jl] = acc;
    __syncthreads();

    if (t < 64) {
        const int idx = b * Dout + j;
        float I   = red[0][t] + red[1][t] + red[2][t] + red[3][t] + bias[j];
        float v   = fmaf(BETA, u0[idx], I);
        float vt  = v - THRESH;
        float spk = vt > 0.f ? 1.f : 0.f;
        float a   = 1.f + fabsf(vt);
        float om  = 1.f - THRESH / (a * a);

        out_spk[idx]  = spk;
        out_u[idx]    = v - THRESH * spk;
        out_Eb[idx]   = om * fmaf(BETA, E_b[idx], 1.f);
        one_m_ws[idx] = om;
    }
}

// ---------------------------------------------------------------------------
// B: the 512 MB E_W stream.
// R6 post-mortem: v0=gid<<1 put adjacent LANES 32 B apart -> each load
// instruction swept its window at stride-32 (50% coalescing). Fix: block owns
// 512 consecutive vec4s (8 KB); thread t handles v0 = blk*512+t and
// v1 = v0+256. Both loads/stores are perfect contiguous 1 KB/wave
// transactions AND two independent HBM ops in flight per thread.
// Layout bonus: v0,v1 = same sample b, same column-vec4 (rows i, i+1)
// -> ONE one_m load serves both; the two x scalars are wave-uniform.
// 32768 blocks x 256 threads, no loop (MLP from occupancy, proven R0),
// plain stores (nt proven 2x slower, R2/R3).
// E_W_new[b,i,j] = one_m[b,j] * (BETA*E_W[b,i,j] + x[b,i])
// ---------------------------------------------------------------------------
__global__ __launch_bounds__(256) void ew_update(const float* __restrict__ E_W,
                                                 const float* __restrict__ x,
                                                 const float* __restrict__ one_m,
                                                 float* __restrict__ out_EW) {
    const unsigned t   = threadIdx.x;
    const unsigned v0  = blockIdx.x * 512u + t;     // block: 512 consec vec4s
    const unsigned v1  = v0 + 256u;

    const f4* __restrict__ src = (const f4*)E_W;
    f4* __restrict__       dst = (f4*)out_EW;
    const f4* __restrict__ om4 = (const f4*)one_m;

    // two independent, fully-coalesced HBM loads in flight
    const f4 e0 = src[v0];
    const f4 e1 = src[v1];

    const unsigned b   = v0 >> 18;          // sample (shared by v0,v1)
    const unsigned rem = v0 & 262143u;
    const unsigned i0  = rem >> 8;          // row of v0; v1 is row i0+1
    const unsigned jv  = rem & 255u;        // column vec4 (== t, shared)

    const f4    m   = om4[(b << 8) | jv];   // one load serves both halves
    const float xs0 = x[(b << 10) | i0];        // wave-uniform
    const float xs1 = x[(b << 10) | (i0 + 1u)]; // wave-uniform

    f4 r0, r1;
    r0.x = m.x * fmaf(BETA, e0.x, xs0); r0.y = m.y * fmaf(BETA, e0.y, xs0);
    r0.z = m.z * fmaf(BETA, e0.z, xs0); r0.w = m.w * fmaf(BETA, e0.w, xs0);
    r1.x = m.x * fmaf(BETA, e1.x, xs1); r1.y = m.y * fmaf(BETA, e1.y, xs1);
    r1.z = m.z * fmaf(BETA, e1.z, xs1); r1.w = m.w * fmaf(BETA, e1.w, xs1);

    dst[v0] = r0;
    dst[v1] = r1;
}

extern "C" void kernel_launch(void* const* d_in, const int* in_sizes, int n_in,
                              void* d_out, int out_size, void* d_ws, size_t ws_size,
                              hipStream_t stream) {
    const float* x    = (const float*)d_in[0];
    const float* W    = (const float*)d_in[1];
    const float* bias = (const float*)d_in[2];
    const float* u0   = (const float*)d_in[3];
    const float* E_W  = (const float*)d_in[4];
    const float* E_b  = (const float*)d_in[5];

    float* out     = (float*)d_out;
    float* out_spk = out;                       // [64,1024]
    float* out_u   = out + NBJ;                 // [64,1024]
    float* out_EW  = out + 2 * NBJ;             // [64,1024,1024]
    float* out_Eb  = out + 2 * NBJ + (size_t)Bsz * Din * Dout;  // [64,1024]

    float* one_m = (float*)d_ws;                // 256 KB

    gemm_lif<<<Bsz * (Dout / 64), 256, 0, stream>>>(x, W, bias, u0, E_b,
                                                    out_spk, out_u, out_Eb, one_m);
    ew_update<<<(Bsz * Din * Dout / 8) / 256, 256, 0, stream>>>(E_W, x, one_m, out_EW);
}

// Round 8
// 453.061 us; speedup vs baseline: 1.0734x; 1.0130x over previous
//
#include <hip/hip_runtime.h>

#define BETA 0.9f
#define THRESH 1.0f

constexpr int Bsz  = 64;
constexpr int Din  = 1024;
constexpr int Dout = 1024;
constexpr int NBJ  = Bsz * Dout;        // 65536

typedef float f4 __attribute__((ext_vector_type(4)));

// ---------------------------------------------------------------------------
// A: fused GEMM + LIF elementwise (byte-identical to R4/R6/R7 — ~12 us).
// grid = Bsz * (Dout/64) = 1024 blocks x 256 threads.
// ---------------------------------------------------------------------------
__global__ __launch_bounds__(256) void gemm_lif(const float* __restrict__ x,
                                                const float* __restrict__ W,
                                                const float* __restrict__ bias,
                                                const float* __restrict__ u0,
                                                const float* __restrict__ E_b,
                                                float* __restrict__ out_spk,
                                                float* __restrict__ out_u,
                                                float* __restrict__ out_Eb,
                                                float* __restrict__ one_m_ws) {
    __shared__ float red[4][64];
    const int blk = blockIdx.x;
    const int b   = blk >> 4;           // sample 0..63
    const int jg  = blk & 15;           // 64-column group
    const int t   = threadIdx.x;
    const int jl  = t & 63;
    const int ks  = t >> 6;             // k-slice == wave id
    const int j   = (jg << 6) + jl;

    const float* xr = x + b * Din + (ks << 8);
    const float* Wc = W + (size_t)(ks << 8) * Dout + j;

    float acc = 0.f;
#pragma unroll 16
    for (int k = 0; k < 256; ++k)
        acc = fmaf(xr[k], Wc[(size_t)k * Dout], acc);

    red[ks][jl] = acc;
    __syncthreads();

    if (t < 64) {
        const int idx = b * Dout + j;
        float I   = red[0][t] + red[1][t] + red[2][t] + red[3][t] + bias[j];
        float v   = fmaf(BETA, u0[idx], I);
        float vt  = v - THRESH;
        float spk = vt > 0.f ? 1.f : 0.f;
        float a   = 1.f + fabsf(vt);
        float om  = 1.f - THRESH / (a * a);

        out_spk[idx]  = spk;
        out_u[idx]    = v - THRESH * spk;
        out_Eb[idx]   = om * fmaf(BETA, E_b[idx], 1.f);
        one_m_ws[idx] = om;
    }
}

// ---------------------------------------------------------------------------
// B: the 512 MB E_W stream — EXACT R0 shape, the fastest measured variant
// (~105 us vs 117-185 for every "improved" version).
// One float4 per thread, no loop, plain store: zero in-thread memory-op
// serialization; MLP comes entirely from TLP (65536 blocks x 4 waves,
// ~8+ blocks resident/CU with a deep backlog). Ladder evidence R0-R7:
// per-thread op count is monotone with time; 1 is optimal. nt stores are a
// ~2.3 TB/s capped path on gfx950 (R2/R3, two structures, same rate) — plain.
// E_W_new[b,i,j] = one_m[b,j] * (BETA*E_W[b,i,j] + x[b,i])
// ---------------------------------------------------------------------------
__global__ __launch_bounds__(256) void ew_update(const float* __restrict__ E_W,
                                                 const float* __restrict__ x,
                                                 const float* __restrict__ one_m,
                                                 float* __restrict__ out_EW) {
    const unsigned vidx = blockIdx.x * 256u + threadIdx.x;  // vec4 idx < 2^24
    const unsigned b    = vidx >> 18;        // sample
    const unsigned rem  = vidx & 262143u;
    const unsigned i    = rem >> 8;          // row within sample
    const unsigned jv   = rem & 255u;        // column vec4

    const float xs = x[(b << 10) | i];                       // block-uniform
    const f4    m  = ((const f4*)one_m)[(b << 8) | jv];      // L2-resident
    const f4    e  = ((const f4*)E_W)[vidx];                 // coalesced 16B/lane

    f4 r;
    r.x = m.x * fmaf(BETA, e.x, xs);
    r.y = m.y * fmaf(BETA, e.y, xs);
    r.z = m.z * fmaf(BETA, e.z, xs);
    r.w = m.w * fmaf(BETA, e.w, xs);
    ((f4*)out_EW)[vidx] = r;
}

extern "C" void kernel_launch(void* const* d_in, const int* in_sizes, int n_in,
                              void* d_out, int out_size, void* d_ws, size_t ws_size,
                              hipStream_t stream) {
    const float* x    = (const float*)d_in[0];
    const float* W    = (const float*)d_in[1];
    const float* bias = (const float*)d_in[2];
    const float* u0   = (const float*)d_in[3];
    const float* E_W  = (const float*)d_in[4];
    const float* E_b  = (const float*)d_in[5];

    float* out     = (float*)d_out;
    float* out_spk = out;                       // [64,1024]
    float* out_u   = out + NBJ;                 // [64,1024]
    float* out_EW  = out + 2 * NBJ;             // [64,1024,1024]
    float* out_Eb  = out + 2 * NBJ + (size_t)Bsz * Din * Dout;  // [64,1024]

    float* one_m = (float*)d_ws;                // 256 KB

    gemm_lif<<<Bsz * (Dout / 64), 256, 0, stream>>>(x, W, bias, u0, E_b,
                                                    out_spk, out_u, out_Eb, one_m);
    ew_update<<<(Bsz * Din * Dout / 4) / 256, 256, 0, stream>>>(E_W, x, one_m, out_EW);
}